// Round 9
// baseline (411.331 us; speedup 1.0000x reference)
//
#include <hip/hip_runtime.h>
#include <hip/hip_bf16.h>
#include <stdint.h>

#define D_IN  4096
#define D_OUT 4096
#define MROWS 8192   // 2 * 4096 rows of x

using i32x4 = __attribute__((ext_vector_type(4))) int;

// -------- Kernel 1 (fused): RMSNorm -> i8 xn (per-row absmax scale)
//          AND w_q fp32 -> i8 (exact, values in {-1,0,1}) ------------------
// One row per wave (R8, neutral vs block-version => BW-floor). Blocks
// [0,2048): 4 rows/block. Blocks [2048, 2048+4096): w_q conversion.
__global__ __launch_bounds__(256) void prep_kernel(
    const float* __restrict__ x, const float* __restrict__ nw,
    signed char* __restrict__ xq, float* __restrict__ srow,
    const float* __restrict__ wq, signed char* __restrict__ wb) {
  const int b = blockIdx.x;
  const int t = threadIdx.x;

  if (b < 2048) {
    const int lane = t & 63;
    const int row  = b * 4 + (t >> 6);
    const float4* xr  = (const float4*)(x + (size_t)row * D_IN);
    const float4* nw4 = (const float4*)nw;

    float4 p[16];
    float ss = 0.f, mx = 0.f;
#pragma unroll
    for (int c = 0; c < 4; ++c) {
      float4 v[4], w[4];
#pragma unroll
      for (int i = 0; i < 4; ++i) {
        v[i] = xr[(c * 4 + i) * 64 + lane];
        w[i] = nw4[(c * 4 + i) * 64 + lane];
      }
#pragma unroll
      for (int i = 0; i < 4; ++i) {
        ss += v[i].x * v[i].x + v[i].y * v[i].y +
              v[i].z * v[i].z + v[i].w * v[i].w;
        float4 pp;
        pp.x = v[i].x * w[i].x; pp.y = v[i].y * w[i].y;
        pp.z = v[i].z * w[i].z; pp.w = v[i].w * w[i].w;
        p[c * 4 + i] = pp;
        mx = fmaxf(mx, fmaxf(fmaxf(fabsf(pp.x), fabsf(pp.y)),
                             fmaxf(fabsf(pp.z), fabsf(pp.w))));
      }
    }
#pragma unroll
    for (int off = 1; off < 64; off <<= 1) {
      ss += __shfl_xor(ss, off, 64);
      mx = fmaxf(mx, __shfl_xor(mx, off, 64));
    }
    const float scale  = rsqrtf(ss * (1.0f / D_IN) + 1e-6f);
    const float rowmax = mx * scale;
    const float s = fmaxf(rowmax, 1e-20f) * (1.0f / 127.0f);
    const float f = scale / s;   // = scale * 127 / rowmax
    if (lane == 0) srow[row] = s;

    int* out = (int*)(xq + (size_t)row * D_IN);
#pragma unroll
    for (int i = 0; i < 16; ++i) {
      const int q0 = (int)rintf(p[i].x * f);
      const int q1 = (int)rintf(p[i].y * f);
      const int q2 = (int)rintf(p[i].z * f);
      const int q3 = (int)rintf(p[i].w * f);
      out[i * 64 + lane] =
          (q0 & 0xFF) | ((q1 & 0xFF) << 8) | ((q2 & 0xFF) << 16) | (q3 << 24);
    }
  } else {
    // ---- w_q conversion, fully coalesced (proven) ----
    const int cb = b - 2048;
    const float4* w4 = (const float4*)wq;
    int* o = (int*)wb;
#pragma unroll
    for (int i = 0; i < 4; ++i) {
      const int idx = cb * 1024 + i * 256 + t;
      const float4 v = w4[idx];
      const int q0 = (int)v.x, q1 = (int)v.y, q2 = (int)v.z, q3 = (int)v.w;
      o[idx] = (q0 & 0xFF) | ((q1 & 0xFF) << 8) | ((q2 & 0xFF) << 16) | (q3 << 24);
    }
  }
}

// ---------------- Kernel 2: i8 GEMM (A: MxK, B: NxK i.e. B^T) -------------
// mfma_i32_16x16x64_i8: per lane A[m=lane&15][k=(lane>>4)*16 + j], j in [0,16).
// C/D layout (shape-determined): col=lane&15, row=(lane>>4)*4+reg.
// LDS XOR-swizzle (proven 0 conflicts, 16-row frag pattern): 16B chunk
// (row, j) at slot j ^ ((row>>1)&3), applied on the global source,
// compensated in the ds_read address. Row stride 64 B unchanged.
//
// R9 = R5 schedule rescaled to 128x128 / 4 waves / 2 BLOCKS PER CU.
// Diagnosis: 6 failed in-block schedule experiments (R2/3/4/7/8) say the
// 1-block barrier lockstep is structural; the untried lever is block-level
// decoupling (when block A waits at a barrier/vmcnt, block B keeps the
// MFMA + LDS pipes busy). 256^2 can't fit 2 blocks (acc+frag regs);
// 128^2 with wave tile 64x64 can: acc 64 + frag-dbuf 64 + addr ~30 =
// ~160 regs (<=256 bucket -> 8 waves/CU) and ring-4 LDS = 64 KB -> 2
// blocks = 128 KB <= 160 KB. External support: m103 tile scan - at
// simple-barrier structures 128^2 (3 blk/CU, 912 TF) beat 256^2 (792).
//
// Schedule IDENTICAL to R5 (proven): 4-deep ring, stage 3-ahead (4
// global_load_lds per tile), reg fragment double-buffer (read T+1 while
// computing T), WVM(4) counted wait (lands tile T+2, never drains to 0 in
// the main loop), one barrier per body.
#define BM 128
#define BN 128
#define BKB 64                  // K bytes per tile == one MFMA k-step
#define NKT (D_IN / BKB)        // 64 K-tiles
#define SLOT_BYTES (BM * BKB)   // 8 KB per ring slot per operand

#define WVM(n_) asm volatile("s_waitcnt vmcnt(" #n_ ")" ::: "memory")
#define BAR()   __builtin_amdgcn_s_barrier()

// Stage tile t_ (A+B, 2+2 global_load_lds, 16B/lane) into ring slot t_&3.
#define STAGE(t_)                                                             \
  do {                                                                        \
    _Pragma("unroll") for (int _i = 0; _i < 2; ++_i)                          \
        __builtin_amdgcn_global_load_lds(                                     \
            (__attribute__((address_space(1))) void*)(A + aOff[_i] +          \
                                                      (t_) * BKB),            \
            (__attribute__((address_space(3))) void*)&sA[(t_) & 3]            \
                                                       [ldsOff[_i]],          \
            16, 0, 0);                                                        \
    _Pragma("unroll") for (int _i = 0; _i < 2; ++_i)                          \
        __builtin_amdgcn_global_load_lds(                                     \
            (__attribute__((address_space(1))) void*)(B + bOff[_i] +          \
                                                      (t_) * BKB),            \
            (__attribute__((address_space(3))) void*)&sB[(t_) & 3]            \
                                                       [ldsOff[_i]],          \
            16, 0, 0);                                                        \
  } while (0)

// Read tile t_'s fragments from ring slot t_&3 into register arrays
// fa_/fb_ (4 A + 4 B ds_read_b128).
#define READF(t_, fa_, fb_)                                                   \
  do {                                                                        \
    _Pragma("unroll") for (int _i = 0; _i < 4; ++_i)                          \
        fa_[_i] = *(const i32x4*)&sA[(t_) & 3][aoff0 + _i * (16 * BKB)];      \
    _Pragma("unroll") for (int _j = 0; _j < 4; ++_j)                          \
        fb_[_j] = *(const i32x4*)&sB[(t_) & 3][boff0 + _j * (16 * BKB)];      \
  } while (0)

// 16-MFMA cluster on register fragments fa_/fb_.
#define MFMA_C(fa_, fb_)                                                      \
  do {                                                                        \
    __builtin_amdgcn_s_setprio(1);                                            \
    _Pragma("unroll") for (int _i = 0; _i < 4; ++_i)                          \
        _Pragma("unroll") for (int _j = 0; _j < 4; ++_j)                      \
            acc[_i][_j] = __builtin_amdgcn_mfma_i32_16x16x64_i8(              \
                fa_[_i], fb_[_j], acc[_i][_j], 0, 0, 0);                      \
    __builtin_amdgcn_s_setprio(0);                                            \
  } while (0)

// Body T: prefetch tile T+1's fragments into fn*, stage tile T+3, compute
// tile T from fc*, counted wait (lands T+2), barrier.
#define BODY(T_, fcA_, fcB_, fnA_, fnB_, STG_, WAIT_)                         \
  do {                                                                        \
    READF((T_) + 1, fnA_, fnB_);                                              \
    STG_;                                                                     \
    MFMA_C(fcA_, fcB_);                                                       \
    WAIT_;                                                                    \
    BAR();                                                                    \
  } while (0)

__global__ __launch_bounds__(256, 2) void gemm_kernel(
    const signed char* __restrict__ A,   // MROWS x D_IN i8
    const signed char* __restrict__ B,   // D_OUT x D_IN i8
    const float* __restrict__ srow,      // MROWS   (per-row dequant scale)
    const float* __restrict__ gamma,     // D_OUT
    float* __restrict__ C) {             // MROWS x D_OUT fp32
  __shared__ __align__(16) signed char sA[4][SLOT_BYTES];  // 32 KB
  __shared__ __align__(16) signed char sB[4][SLOT_BYTES];  // 32 KB

  const int tid  = threadIdx.x;
  const int lane = tid & 63;
  const int wv   = tid >> 6;     // 0..3 (one wave per SIMD)
  const int wm   = wv >> 1;      // 0..1: 64-row half of the 128-row tile
  const int wn   = wv & 1;       // 0..1: 64-col half of the 128-col tile
  const int bn   = blockIdx.x;   // 0..31
  const int bm   = blockIdx.y;   // 0..63

  i32x4 acc[4][4];
#pragma unroll
  for (int i = 0; i < 4; ++i)
#pragma unroll
    for (int j = 0; j < 4; ++j) acc[i][j] = (i32x4){0, 0, 0, 0};

  // Staging map: per tile per operand 512 chunks of 16B; chunk
  // c = i*256 + tid -> tile row r = c>>2, swizzled k-byte offset.
  size_t aOff[2], bOff[2];
  int ldsOff[2];
#pragma unroll
  for (int i = 0; i < 2; ++i) {
    const int c  = i * 256 + tid;
    const int r  = c >> 2;
    const int cc = ((c & 3) ^ ((r >> 1) & 3)) * 16;
    aOff[i] = (size_t)(bm * BM + r) * D_IN + cc;
    bOff[i] = (size_t)(bn * BN + r) * D_IN + cc;
    ldsOff[i] = (i * 256 + wv * 64) * 16;  // wave-uniform base; +lane*16 by HW
  }

  // Fragment read offsets (swizzle-compensated; row base is a multiple of
  // 16 so (row>>1)&3 == (lane>>1)&3).
  const int kk    = (((lane >> 4) ^ ((lane >> 1) & 3))) * 16;
  const int aoff0 = (wm * 64 + (lane & 15)) * BKB + kk;
  const int boff0 = (wn * 64 + (lane & 15)) * BKB + kk;

  i32x4 f0a[4], f0b[4], f1a[4], f1b[4];

  // Prologue: stage tiles 0..2; WVM(4) lands tiles 0,1 (tile 2 in flight);
  // barrier publishes; preload tile 0's fragments.
  STAGE(0); STAGE(1); STAGE(2);
  WVM(4);
  BAR();
  READF(0, f0a, f0b);

  // Main loop (2-body unroll for the f0/f1 ping-pong). Bodies 0..59.
#pragma unroll 1
  for (int T = 0; T < NKT - 4; T += 2) {
    BODY(T,     f0a, f0b, f1a, f1b, STAGE(T + 3), WVM(4));
    BODY(T + 1, f1a, f1b, f0a, f0b, STAGE(T + 4), WVM(4));
  }
  // Tail: bodies 60..63 (stages issued through tile 62 by the loop).
  BODY(60, f0a, f0b, f1a, f1b, STAGE(63), WVM(4));
  BODY(61, f1a, f1b, f0a, f0b, ,          WVM(0));   // tile 63 lands here
  READF(63, f1a, f1b);
  MFMA_C(f0a, f0b);
  MFMA_C(f1a, f1b);

  // Epilogue: y = acc * srow[row] * gamma[col]
  const int col0 = bn * BN + wn * 64 + (lane & 15);
  const int row0 = bm * BM + wm * 64 + ((lane >> 4) * 4);
  float g[4];
#pragma unroll
  for (int j = 0; j < 4; ++j) g[j] = gamma[col0 + j * 16];

#pragma unroll
  for (int i = 0; i < 4; ++i) {
#pragma unroll
    for (int r = 0; r < 4; ++r) {
      const int row = row0 + i * 16 + r;
      const float sr = srow[row];
#pragma unroll
      for (int j = 0; j < 4; ++j) {
        C[(size_t)row * D_OUT + col0 + j * 16] =
            (float)acc[i][j][r] * sr * g[j];
      }
    }
  }
}

#undef BODY
#undef MFMA_C
#undef READF
#undef STAGE
#undef WVM
#undef BAR

extern "C" void kernel_launch(void* const* d_in, const int* in_sizes, int n_in,
                              void* d_out, int out_size, void* d_ws, size_t ws_size,
                              hipStream_t stream) {
  const float* x     = (const float*)d_in[0];  // (2,4096,4096)
  const float* nw    = (const float*)d_in[1];  // (4096,)
  const float* wq    = (const float*)d_in[2];  // (4096,4096) {-1,0,1}
  const float* gamma = (const float*)d_in[3];  // (4096,)
  float* y = (float*)d_out;

  // Workspace: xq i8 (32 MB) | wb i8 (16 MB) | srow fp32 (32 KB)
  signed char* xq = (signed char*)d_ws;
  signed char* wb = xq + (size_t)MROWS * D_IN;
  float* srow = (float*)(wb + (size_t)D_OUT * D_IN);

  // 2048 rmsnorm blocks (1 row/wave) + 4096 w-conversion blocks
  prep_kernel<<<2048 + 4096, 256, 0, stream>>>(x, nw, xq, srow, wq, wb);

  gemm_kernel<<<dim3(D_OUT / BN, MROWS / BM), 256, 0, stream>>>(xq, wb, srow, gamma, y);
}

// Round 10
// 379.136 us; speedup vs baseline: 1.0849x; 1.0849x over previous
//
#include <hip/hip_runtime.h>
#include <hip/hip_bf16.h>
#include <stdint.h>

#define D_IN  4096
#define D_OUT 4096
#define MROWS 8192   // 2 * 4096 rows of x

using i32x4 = __attribute__((ext_vector_type(4))) int;

// -------- Kernel 1 (fused): RMSNorm -> i8 xn (per-row absmax scale)
//          AND w_q fp32 -> i8 (exact, values in {-1,0,1}) ------------------
// One row per wave (R8, neutral vs block-version => BW-floor). Blocks
// [0,2048): 4 rows/block. Blocks [2048, 2048+4096): w_q conversion.
__global__ __launch_bounds__(256) void prep_kernel(
    const float* __restrict__ x, const float* __restrict__ nw,
    signed char* __restrict__ xq, float* __restrict__ srow,
    const float* __restrict__ wq, signed char* __restrict__ wb) {
  const int b = blockIdx.x;
  const int t = threadIdx.x;

  if (b < 2048) {
    const int lane = t & 63;
    const int row  = b * 4 + (t >> 6);
    const float4* xr  = (const float4*)(x + (size_t)row * D_IN);
    const float4* nw4 = (const float4*)nw;

    float4 p[16];
    float ss = 0.f, mx = 0.f;
#pragma unroll
    for (int c = 0; c < 4; ++c) {
      float4 v[4], w[4];
#pragma unroll
      for (int i = 0; i < 4; ++i) {
        v[i] = xr[(c * 4 + i) * 64 + lane];
        w[i] = nw4[(c * 4 + i) * 64 + lane];
      }
#pragma unroll
      for (int i = 0; i < 4; ++i) {
        ss += v[i].x * v[i].x + v[i].y * v[i].y +
              v[i].z * v[i].z + v[i].w * v[i].w;
        float4 pp;
        pp.x = v[i].x * w[i].x; pp.y = v[i].y * w[i].y;
        pp.z = v[i].z * w[i].z; pp.w = v[i].w * w[i].w;
        p[c * 4 + i] = pp;
        mx = fmaxf(mx, fmaxf(fmaxf(fabsf(pp.x), fabsf(pp.y)),
                             fmaxf(fabsf(pp.z), fabsf(pp.w))));
      }
    }
#pragma unroll
    for (int off = 1; off < 64; off <<= 1) {
      ss += __shfl_xor(ss, off, 64);
      mx = fmaxf(mx, __shfl_xor(mx, off, 64));
    }
    const float scale  = rsqrtf(ss * (1.0f / D_IN) + 1e-6f);
    const float rowmax = mx * scale;
    const float s = fmaxf(rowmax, 1e-20f) * (1.0f / 127.0f);
    const float f = scale / s;   // = scale * 127 / rowmax
    if (lane == 0) srow[row] = s;

    int* out = (int*)(xq + (size_t)row * D_IN);
#pragma unroll
    for (int i = 0; i < 16; ++i) {
      const int q0 = (int)rintf(p[i].x * f);
      const int q1 = (int)rintf(p[i].y * f);
      const int q2 = (int)rintf(p[i].z * f);
      const int q3 = (int)rintf(p[i].w * f);
      out[i * 64 + lane] =
          (q0 & 0xFF) | ((q1 & 0xFF) << 8) | ((q2 & 0xFF) << 16) | (q3 << 24);
    }
  } else {
    // ---- w_q conversion, fully coalesced (proven) ----
    const int cb = b - 2048;
    const float4* w4 = (const float4*)wq;
    int* o = (int*)wb;
#pragma unroll
    for (int i = 0; i < 4; ++i) {
      const int idx = cb * 1024 + i * 256 + t;
      const float4 v = w4[idx];
      const int q0 = (int)v.x, q1 = (int)v.y, q2 = (int)v.z, q3 = (int)v.w;
      o[idx] = (q0 & 0xFF) | ((q1 & 0xFF) << 8) | ((q2 & 0xFF) << 16) | (q3 << 24);
    }
  }
}

// ---------------- Kernel 2: i8 GEMM (A: MxK, B: NxK i.e. B^T) -------------
// mfma_i32_16x16x64_i8: per lane A[m=lane&15][k=(lane>>4)*16 + j], j in [0,16).
// C/D layout (shape-determined): col=lane&15, row=(lane>>4)*4+reg.
// LDS XOR-swizzle (proven 0 conflicts): 16B chunk (row, j) at slot
// j ^ ((row>>1)&3), applied on the global source, compensated in ds_read.
//
// R10 = R5-EXACT skeleton (best: 130us. 256x256 tile, 8 waves 2Mx4N,
// BKB=64, 4-deep A+B LDS ring, 1 barrier/body, WVM(4) counted waits,
// reg-level fragment double-buffer f0/f1) + MFMA<->DS ISSUE INTERLEAVE.
//
// Diagnosis (R9 post-mortem, units-corrected): per K-tile-slot, MFMA =
// 64/SIMD x 20cyc = 1280 cyc; LDS port = 96KB reads + 32KB DMA ~ 1150 cyc;
// measured slot = 2437 cyc = 1280 + 1150 -> the two pipes are FULLY
// SERIALIZED. Cause: per-wave in-order issue + MFMA issue back-pressure
// (a wave issuing its 32-MFMA cluster is pinned ~1280 cyc and cannot issue
// the next body's ds_reads; both waves/SIMD are barrier-aligned so the
// port only runs while the MFMA pipe idles). Section reordering (R8)
// cannot fix this; the reads must be EMITTED BETWEEN the MFMAs so they
// issue in the ~18 free slots between consecutive MFMA issues.
// sched_group_barrier pattern per body: 4 x {3 DS_READ, 1 VMEM, 8 MFMA}
// (exactly 12 ds_read + 4 global_load_lds + 32 MFMA). Legal: our reads are
// pure prefetch (consumed NEXT body) - no lgkm dependency inside the body,
// so the scheduler can honor the pattern; SGB cannot break dependencies
// (math unchanged). s_setprio removed (m190: null-to-negative without
// phase role-split).
#define BM 256
#define BN 256
#define BKB 64                  // K bytes per tile == one MFMA k-step
#define NKT (D_IN / BKB)        // 64 K-tiles
#define SLOT_BYTES (BM * BKB)   // 16 KB per ring slot per operand

#define WVM(n_) asm volatile("s_waitcnt vmcnt(" #n_ ")" ::: "memory")
#define BAR()   __builtin_amdgcn_s_barrier()
#define SGB(m_, n_) __builtin_amdgcn_sched_group_barrier((m_), (n_), 0)

// Emission pattern for a full body (12 DS_READ / 4 VMEM / 32 MFMA):
// interleave so the port fills the MFMA issue shadow.
#define SGB_FULL()                                                            \
  do {                                                                        \
    _Pragma("unroll") for (int _g = 0; _g < 4; ++_g) {                        \
      SGB(0x100, 3);  /* 3 x ds_read      */                                  \
      SGB(0x010, 1);  /* 1 x vmem (gload_lds) */                              \
      SGB(0x008, 8);  /* 8 x mfma         */                                  \
    }                                                                         \
  } while (0)
// Variant without staging (tail bodies): 12 DS_READ / 32 MFMA.
#define SGB_NOVM()                                                            \
  do {                                                                        \
    _Pragma("unroll") for (int _g = 0; _g < 4; ++_g) {                        \
      SGB(0x100, 3);                                                          \
      SGB(0x008, 8);                                                          \
    }                                                                         \
  } while (0)

// Stage tile t_ (A+B, 2+2 global_load_lds, 16B/lane) into ring slot t_&3.
#define STAGE(t_)                                                             \
  do {                                                                        \
    _Pragma("unroll") for (int _i = 0; _i < 2; ++_i)                          \
        __builtin_amdgcn_global_load_lds(                                     \
            (__attribute__((address_space(1))) void*)(A + aOff[_i] +          \
                                                      (t_) * BKB),            \
            (__attribute__((address_space(3))) void*)&sA[(t_) & 3]            \
                                                       [ldsOff[_i]],          \
            16, 0, 0);                                                        \
    _Pragma("unroll") for (int _i = 0; _i < 2; ++_i)                          \
        __builtin_amdgcn_global_load_lds(                                     \
            (__attribute__((address_space(1))) void*)(B + bOff[_i] +          \
                                                      (t_) * BKB),            \
            (__attribute__((address_space(3))) void*)&sB[(t_) & 3]            \
                                                       [ldsOff[_i]],          \
            16, 0, 0);                                                        \
  } while (0)

// Read tile t_'s fragments from ring slot t_&3 into register arrays fa_/fb_.
#define READF(t_, fa_, fb_)                                                   \
  do {                                                                        \
    _Pragma("unroll") for (int _i = 0; _i < 8; ++_i)                          \
        fa_[_i] = *(const i32x4*)&sA[(t_) & 3][aoff0 + _i * (16 * BKB)];      \
    _Pragma("unroll") for (int _j = 0; _j < 4; ++_j)                          \
        fb_[_j] = *(const i32x4*)&sB[(t_) & 3][boff0 + _j * (16 * BKB)];      \
  } while (0)

// 32-MFMA cluster on register fragments fa_/fb_ (no setprio: m190).
#define MFMA_C(fa_, fb_)                                                      \
  do {                                                                        \
    _Pragma("unroll") for (int _i = 0; _i < 8; ++_i)                          \
        _Pragma("unroll") for (int _j = 0; _j < 4; ++_j)                      \
            acc[_i][_j] = __builtin_amdgcn_mfma_i32_16x16x64_i8(              \
                fa_[_i], fb_[_j], acc[_i][_j], 0, 0, 0);                      \
  } while (0)

// Body T: prefetch tile T+1's fragments into fn*, stage tile T+3, compute
// tile T from fc*, emission-interleave directive, counted wait, barrier.
#define BODY(T_, fcA_, fcB_, fnA_, fnB_, STG_, SGB_, WAIT_)                   \
  do {                                                                        \
    READF((T_) + 1, fnA_, fnB_);                                              \
    STG_;                                                                     \
    MFMA_C(fcA_, fcB_);                                                       \
    SGB_;                                                                     \
    WAIT_;                                                                    \
    BAR();                                                                    \
  } while (0)

__global__ __launch_bounds__(512, 2) void gemm_kernel(
    const signed char* __restrict__ A,   // MROWS x D_IN i8
    const signed char* __restrict__ B,   // D_OUT x D_IN i8
    const float* __restrict__ srow,      // MROWS   (per-row dequant scale)
    const float* __restrict__ gamma,     // D_OUT
    float* __restrict__ C) {             // MROWS x D_OUT fp32
  __shared__ __align__(16) signed char sA[4][SLOT_BYTES];  // 64 KB
  __shared__ __align__(16) signed char sB[4][SLOT_BYTES];  // 64 KB

  const int tid  = threadIdx.x;
  const int lane = tid & 63;
  const int wv   = tid >> 6;     // 0..7
  const int wm   = wv >> 2;      // 0..1: 128-row half of the 256-row tile
  const int wn   = wv & 3;       // 0..3: 64-col quarter of the 256-col tile
  const int bn   = blockIdx.x;   // 0..15
  const int bm   = blockIdx.y;   // 0..31

  i32x4 acc[8][4];
#pragma unroll
  for (int i = 0; i < 8; ++i)
#pragma unroll
    for (int j = 0; j < 4; ++j) acc[i][j] = (i32x4){0, 0, 0, 0};

  // Staging map (proven): per tile per operand 1024 chunks of 16B; chunk
  // c = i*512 + tid -> tile row r = c>>2, swizzled k-byte offset.
  size_t aOff[2], bOff[2];
  int ldsOff[2];
#pragma unroll
  for (int i = 0; i < 2; ++i) {
    const int c  = i * 512 + tid;
    const int r  = c >> 2;
    const int cc = ((c & 3) ^ ((r >> 1) & 3)) * 16;
    aOff[i] = (size_t)(bm * BM + r) * D_IN + cc;
    bOff[i] = (size_t)(bn * BN + r) * D_IN + cc;
    ldsOff[i] = (i * 512 + wv * 64) * 16;  // wave-uniform base; +lane*16 by HW
  }

  // Fragment read offsets (swizzle-compensated; row base is a multiple of
  // 16 so (row>>1)&3 == (lane>>1)&3).
  const int kk    = (((lane >> 4) ^ ((lane >> 1) & 3))) * 16;
  const int aoff0 = (wm * 128 + (lane & 15)) * BKB + kk;
  const int boff0 = (wn * 64  + (lane & 15)) * BKB + kk;

  i32x4 f0a[8], f0b[4], f1a[8], f1b[4];

  // Prologue: stage tiles 0..2; WVM(4) lands tiles 0,1 (tile 2 in flight);
  // barrier publishes; preload tile 0's fragments.
  STAGE(0); STAGE(1); STAGE(2);
  WVM(4);
  BAR();
  READF(0, f0a, f0b);

  // Main loop (2-body unroll for the f0/f1 ping-pong). Bodies 0..59.
#pragma unroll 1
  for (int T = 0; T < NKT - 4; T += 2) {
    BODY(T,     f0a, f0b, f1a, f1b, STAGE(T + 3), SGB_FULL(), WVM(4));
    BODY(T + 1, f1a, f1b, f0a, f0b, STAGE(T + 4), SGB_FULL(), WVM(4));
  }
  // Tail: bodies 60..63 (stages issued through tile 62 by the loop).
  BODY(60, f0a, f0b, f1a, f1b, STAGE(63), SGB_FULL(), WVM(4));
  BODY(61, f1a, f1b, f0a, f0b, ,          SGB_NOVM(), WVM(0)); // tile 63 lands
  // Body 62: read tile 63 (slot 3), compute 62. No further DMA.
  READF(63, f1a, f1b);
  MFMA_C(f0a, f0b);
  SGB_NOVM();
  // Body 63.
  MFMA_C(f1a, f1b);

  // Epilogue: y = acc * srow[row] * gamma[col]
  const int col0 = bn * BN + wn * 64 + (lane & 15);
  const int row0 = bm * BM + wm * 128 + ((lane >> 4) * 4);
  float g[4];
#pragma unroll
  for (int j = 0; j < 4; ++j) g[j] = gamma[col0 + j * 16];

#pragma unroll
  for (int i = 0; i < 8; ++i) {
#pragma unroll
    for (int r = 0; r < 4; ++r) {
      const int row = row0 + i * 16 + r;
      const float sr = srow[row];
#pragma unroll
      for (int j = 0; j < 4; ++j) {
        C[(size_t)row * D_OUT + col0 + j * 16] =
            (float)acc[i][j][r] * sr * g[j];
      }
    }
  }
}

#undef BODY
#undef MFMA_C
#undef READF
#undef STAGE
#undef SGB_FULL
#undef SGB_NOVM
#undef SGB
#undef WVM
#undef BAR

extern "C" void kernel_launch(void* const* d_in, const int* in_sizes, int n_in,
                              void* d_out, int out_size, void* d_ws, size_t ws_size,
                              hipStream_t stream) {
  const float* x     = (const float*)d_in[0];  // (2,4096,4096)
  const float* nw    = (const float*)d_in[1];  // (4096,)
  const float* wq    = (const float*)d_in[2];  // (4096,4096) {-1,0,1}
  const float* gamma = (const float*)d_in[3];  // (4096,)
  float* y = (float*)d_out;

  // Workspace: xq i8 (32 MB) | wb i8 (16 MB) | srow fp32 (32 KB)
  signed char* xq = (signed char*)d_ws;
  signed char* wb = xq + (size_t)MROWS * D_IN;
  float* srow = (float*)(wb + (size_t)D_OUT * D_IN);

  // 2048 rmsnorm blocks (1 row/wave) + 4096 w-conversion blocks
  prep_kernel<<<2048 + 4096, 256, 0, stream>>>(x, nw, xq, srow, wq, wb);

  gemm_kernel<<<dim3(D_OUT / BN, MROWS / BM), 512, 0, stream>>>(xq, wb, srow, gamma, y);
}